// Round 6
// baseline (434.600 us; speedup 1.0000x reference)
//
#include <hip/hip_runtime.h>
#include <hip/hip_fp16.h>
#include <math.h>

#define BB 32
#define NN 128
#define CC 16
#define OO 32
#define II 32
#define JJ 32
#define MM (NN*CC)

// One block per (b,o), 512 threads. Thread t owns 4 u_hat rows m_r=(c=t>>5,
// n=(t&31)+32r) packed fp16x2 in pu[4][16] (64 VGPRs). All 4 rows share c ->
// one W slice reused. Setup accumulates each row in fp32 (acc[32] transient),
// packs to fp16 (rel err 2^-11, ~1e-3 on outputs vs 2e-2 threshold). The 3
// routing iterations are register math + shuffle butterflies + ~1.3 KB LDS.
//
// Allocator evidence: 1024-thr blocks pin 64 VGPRs and spill (R4/R5, 230-320MB
// scratch); 512-thr + __launch_bounds__(512,2) granted 128 (R3). Peak live
// here ~105 < 128 -> no spill.
__global__ __launch_bounds__(512, 2) void k_caps(
    const float* __restrict__ x, const float* __restrict__ W,
    float* __restrict__ out) {
  __shared__ float swred[8][32];    // per-wave s[j] partials
  __shared__ float vj[32];          // squashed capsule
  __shared__ float red1[8], red2[8];

  int bid = blockIdx.x;
  int b = ((bid & 7) << 2) | ((bid >> 3) & 3);  // XCD-affinity: same-b -> same XCD L2
  int o = bid >> 5;
  int tid = threadIdx.x;
  int lane = tid & 63, wave = tid >> 6;
  int nn = tid & 31;
  int c  = tid >> 5;                // 0..15, shared by this thread's 4 rows

  __half2 pu[4][16];                // u_hat rows, fp16-packed (u[2q],u[2q+1])

  // ---- setup: u_r[j] = sum_i x[b,n_r,c,i] * W[c,o,i,j], one row at a time ----
  const float* wp = W + ((size_t)(c * OO + o) * II) * JJ;
  #pragma unroll
  for (int r = 0; r < 4; ++r) {
    const float* xp = x + ((size_t)(b * NN + (nn + 32 * r)) * CC + c) * II;
    float acc[32];
    #pragma unroll
    for (int j = 0; j < 32; ++j) acc[j] = 0.f;
    for (int q = 0; q < 8; ++q) {   // rolled (code size); constant reg indices inside
      float4 x4 = *(const float4*)(xp + 4 * q);
      #pragma unroll
      for (int rr = 0; rr < 4; ++rr) {
        float xi = (rr == 0) ? x4.x : (rr == 1) ? x4.y : (rr == 2) ? x4.z : x4.w;
        const float* wrow = wp + (size_t)(4 * q + rr) * JJ;  // half-wave-uniform, L1 broadcast
        #pragma unroll
        for (int jq = 0; jq < 8; ++jq) {
          float4 w4 = *(const float4*)(wrow + 4 * jq);
          acc[4*jq+0] = fmaf(xi, w4.x, acc[4*jq+0]);
          acc[4*jq+1] = fmaf(xi, w4.y, acc[4*jq+1]);
          acc[4*jq+2] = fmaf(xi, w4.z, acc[4*jq+2]);
          acc[4*jq+3] = fmaf(xi, w4.w, acc[4*jq+3]);
        }
      }
    }
    #pragma unroll
    for (int h = 0; h < 16; ++h)
      pu[r][h] = __float22half2_rn(make_float2(acc[2*h], acc[2*h+1]));
  }

  // ---- 3 routing iterations, all register/LDS-local ----
  float bv[4] = {0.f, 0.f, 0.f, 0.f};  // my 4 b_ij entries
  float mx = 0.f;
  float rinv = 1.0f / (float)MM;       // softmax(0) == uniform 1/2048

  for (int t = 0; t < 3; ++t) {
    float cf[4];
    #pragma unroll
    for (int r = 0; r < 4; ++r) cf[r] = __expf(bv[r] - mx) * rinv;

    // s[j] partials fused with the h=16 butterfly stage (only sp[16] live)
    float sp[16];
    {
      bool hi16 = (nn & 16) != 0;
      #pragma unroll
      for (int e = 0; e < 16; ++e) {
        float a = 0.f, bq = 0.f;
        #pragma unroll
        for (int r = 0; r < 4; ++r) {
          __half2 pa = pu[r][e >> 1], pb = pu[r][8 + (e >> 1)];
          float ua = (e & 1) ? __high2float(pa) : __low2float(pa);
          float ub = (e & 1) ? __high2float(pb) : __low2float(pb);
          a  = fmaf(cf[r], ua, a);
          bq = fmaf(cf[r], ub, bq);
        }
        float send = hi16 ? a : bq;
        float keep = hi16 ? bq : a;
        sp[e] = keep + __shfl_xor(send, 16);
      }
    }
    // remaining butterfly stages: lane nn ends holding element nn
    #pragma unroll
    for (int h = 8; h >= 1; h >>= 1) {
      bool hi = (nn & h) != 0;
      #pragma unroll
      for (int e = 0; e < 8; ++e) {
        if (e < h) {
          float send = hi ? sp[e] : sp[e + h];
          float keep = hi ? sp[e + h] : sp[e];
          sp[e] = keep + __shfl_xor(send, h);
        }
      }
    }
    float sv = sp[0] + __shfl_xor(sp[0], 32);   // fold the wave's two 32-halves
    if (lane < 32) swred[wave][lane] = sv;
    __syncthreads();

    // squash on 32 threads
    if (tid < 32) {
      float s = 0.f;
      #pragma unroll
      for (int w = 0; w < 8; ++w) s += swred[w][tid];
      float msq = s * s;
      #pragma unroll
      for (int off = 16; off > 0; off >>= 1) msq += __shfl_xor(msq, off);
      float mag = sqrtf(msq) + 1e-11f;
      float a = msq / (1.0f + msq);
      float vv = a * s / mag;
      vj[tid] = vv;
      if (t == 2) {
        out[((size_t)b * OO + o) * JJ + tid] = vv;        // v_j [B,1,O,J]
        if (tid == 0) out[BB * OO * JJ + b * OO + o] = a; // a_j [B,1,O,1]
      }
    }
    __syncthreads();
    if (t == 2) break;   // reference discards the last b_ij update

    // u.v per row (register dot with vj), update b_ij, block softmax stats
    #pragma unroll
    for (int r = 0; r < 4; ++r) {
      float d0 = 0.f, d1 = 0.f;
      #pragma unroll
      for (int q = 0; q < 16; ++q) {
        d0 = fmaf(__low2float(pu[r][q]),  vj[2*q],     d0);
        d1 = fmaf(__high2float(pu[r][q]), vj[2*q + 1], d1);
      }
      bv[r] += d0 + d1;
    }

    float m_ = fmaxf(fmaxf(bv[0], bv[1]), fmaxf(bv[2], bv[3]));
    #pragma unroll
    for (int off = 32; off > 0; off >>= 1) m_ = fmaxf(m_, __shfl_xor(m_, off));
    if (lane == 0) red1[wave] = m_;
    __syncthreads();
    mx = fmaxf(fmaxf(fmaxf(red1[0], red1[1]), fmaxf(red1[2], red1[3])),
               fmaxf(fmaxf(red1[4], red1[5]), fmaxf(red1[6], red1[7])));

    float sx = (__expf(bv[0] - mx) + __expf(bv[1] - mx)) +
               (__expf(bv[2] - mx) + __expf(bv[3] - mx));
    #pragma unroll
    for (int off = 32; off > 0; off >>= 1) sx += __shfl_xor(sx, off);
    if (lane == 0) red2[wave] = sx;
    __syncthreads();
    rinv = 1.0f / (((red2[0] + red2[1]) + (red2[2] + red2[3])) +
                   ((red2[4] + red2[5]) + (red2[6] + red2[7])));
    __syncthreads();   // protect red1/red2/swred reuse next iteration
  }
}

extern "C" void kernel_launch(void* const* d_in, const int* in_sizes, int n_in,
                              void* d_out, int out_size, void* d_ws, size_t ws_size,
                              hipStream_t stream) {
  const float* x = (const float*)d_in[0];   // [B,N,C,I] fp32
  const float* W = (const float*)d_in[1];   // [C,O,I,J] fp32
  (void)in_sizes; (void)n_in; (void)d_ws; (void)ws_size; (void)out_size;
  float* out = (float*)d_out;               // v_j (32768) ++ a_j (1024)
  k_caps<<<BB * OO, 512, 0, stream>>>(x, W, out);
}